// Round 5
// baseline (1062.932 us; speedup 1.0000x reference)
//
#include <hip/hip_runtime.h>
#include <hip/hip_fp16.h>

#define BB 4
#define N0 256
#define N1 256
#define NVOX 65536
#define NSUB 8
#define NLOR 32768
#define RAYLEN 256
#define CH 16
#define NPTS (NLOR * RAYLEN)
#define VOXT 32768   // voxels per LDS tile (1 batch half-plane, 128KB)

// Transpose osem (B, NVOX) planar -> xt (NVOX, 4) so ray gathers are one float4.
__global__ __launch_bounds__(256) void k_transpose(const float* __restrict__ osem,
                                                   float* __restrict__ xt) {
    int v = blockIdx.x * blockDim.x + threadIdx.x;
    if (v >= NVOX) return;
    float4 o;
    o.x = osem[0 * NVOX + v];
    o.y = osem[1 * NVOX + v];
    o.z = osem[2 * NVOX + v];
    o.w = osem[3 * NVOX + v];
    ((float4*)xt)[v] = o;
}

// Pack one subset's ray data: u32 = u16 voxel idx (NVOX=65536 fits exactly) | f16 weight.
// Halves the scan bytes and merges idx+weight into ONE load stream.
__global__ __launch_bounds__(256) void k_pack(const int* __restrict__ ridx,
                                              const float* __restrict__ pw,
                                              unsigned* __restrict__ packed) {
    int t = blockIdx.x * blockDim.x + threadIdx.x;  // over NPTS/4
    int4   id = ((const int4*)ridx)[t];
    float4 w  = ((const float4*)pw)[t];
    uint4 o;
    o.x = (unsigned)id.x | ((unsigned)__half_as_ushort(__float2half_rn(w.x)) << 16);
    o.y = (unsigned)id.y | ((unsigned)__half_as_ushort(__float2half_rn(w.y)) << 16);
    o.z = (unsigned)id.z | ((unsigned)__half_as_ushort(__float2half_rn(w.z)) << 16);
    o.w = (unsigned)id.w | ((unsigned)__half_as_ushort(__float2half_rn(w.w)) << 16);
    ((uint4*)packed)[t] = o;
}

__device__ __forceinline__ float upk_w(unsigned p) {
    return __half2float(__ushort_as_half((unsigned short)(p >> 16)));
}

// Forward projection + ratio per LOR (packed input). One wave per LOR.
__global__ __launch_bounds__(256) void k_fwd_p(
    const unsigned* __restrict__ packed,  // subset's packed stream
    const float* __restrict__ xt,         // (NVOX,4)
    const float* __restrict__ data,       // + index b*NSUB*NLOR + l
    const float* __restrict__ mult,
    const float* __restrict__ contam,
    const float* __restrict__ norm,       // (B)
    float* __restrict__ ratio)            // (NLOR,4)
{
    const int wave = threadIdx.x >> 6;
    const int lane = threadIdx.x & 63;
    const int l = blockIdx.x * 4 + wave;

    uint4 P = ((const uint4*)(packed + (size_t)l * RAYLEN))[lane];
    float ax = 0.f, ay = 0.f, az = 0.f, aw = 0.f;
    unsigned pp[4] = {P.x, P.y, P.z, P.w};
#pragma unroll
    for (int k = 0; k < 4; ++k) {
        float wt = upk_w(pp[k]);
        float4 xv = ((const float4*)xt)[pp[k] & 0xffffu];
        ax += xv.x * wt;
        ay += xv.y * wt;
        az += xv.z * wt;
        aw += xv.w * wt;
    }
#pragma unroll
    for (int off = 32; off >= 1; off >>= 1) {
        ax += __shfl_xor(ax, off);
        ay += __shfl_xor(ay, off);
        az += __shfl_xor(az, off);
        aw += __shfl_xor(aw, off);
    }
    if (lane == 0) {
        float fwd[4] = {ax, ay, az, aw};
        float rr[4];
#pragma unroll
        for (int b = 0; b < 4; ++b) {
            long o = (long)b * (NSUB * NLOR) + l;
            float m = mult[o];
            float e = m * (norm[b] * fwd[b]) + contam[o];
            rr[b] = m * (1.0f - data[o] / e);
        }
        ((float4*)ratio)[l] = make_float4(rr[0], rr[1], rr[2], rr[3]);
    }
}

// Atomic-free backprojection (packed): block (chunk c, group g) accumulates batch
// (g&3), voxel half (g>>2) into a 128KB LDS plane via ds_add_f32; 4 independent
// uint4 loads (16 points) in flight per thread per iteration for latency hiding.
__global__ __launch_bounds__(1024) void k_back_p(
    const unsigned* __restrict__ packed,  // subset's packed stream
    const float* __restrict__ ratio,      // (NLOR,4)
    float* __restrict__ part,             // (C,4,NVOX)
    int PC)                               // points per chunk
{
    __shared__ float acc[VOXT];
    const int c = blockIdx.x;
    const int g = blockIdx.y;         // 0..7
    const int b = g & 3;
    const unsigned lo = (unsigned)(g >> 2) * VOXT;

    for (int q = threadIdx.x; q < VOXT; q += 1024) acc[q] = 0.0f;
    __syncthreads();

    const int n4 = PC >> 2;                        // uint4 elems in this chunk
    const uint4* src = (const uint4*)packed + (size_t)c * n4;
    const int e0 = c * n4;                         // global uint4-elem offset

#define PROC(P, R)                                                            \
    {                                                                         \
        unsigned q0 = (P.x & 0xffffu) - lo, q1 = (P.y & 0xffffu) - lo,        \
                 q2 = (P.z & 0xffffu) - lo, q3 = (P.w & 0xffffu) - lo;        \
        if (q0 < VOXT) atomicAdd(&acc[q0], upk_w(P.x) * R);                   \
        if (q1 < VOXT) atomicAdd(&acc[q1], upk_w(P.y) * R);                   \
        if (q2 < VOXT) atomicAdd(&acc[q2], upk_w(P.z) * R);                   \
        if (q3 < VOXT) atomicAdd(&acc[q3], upk_w(P.w) * R);                   \
    }

    for (int base4 = 0; base4 < n4; base4 += 4096) {
        const int ea = base4 + (int)threadIdx.x;
        uint4 A = src[ea];
        uint4 B = src[ea + 1024];
        uint4 C2 = src[ea + 2048];
        uint4 D = src[ea + 3072];
        // LOR id = point>>8 = uint4elem>>6 ; wave-uniform per load slot
        float ra = ratio[((e0 + ea) >> 6) * 4 + b];
        float rb = ratio[((e0 + ea + 1024) >> 6) * 4 + b];
        float rc = ratio[((e0 + ea + 2048) >> 6) * 4 + b];
        float rd = ratio[((e0 + ea + 3072) >> 6) * 4 + b];
        PROC(A, ra) PROC(B, rb) PROC(C2, rc) PROC(D, rd)
    }
#undef PROC
    __syncthreads();

    float4* dst = (float4*)(part + ((size_t)c * 4 + b) * NVOX + lo);
    const float4* srcl = (const float4*)acc;
    for (int q = threadIdx.x; q < VOXT / 4; q += 1024) dst[q] = srcl[q];
}

// ---------------- raw fallback (R3 path, used if workspace is small) ----------------
__global__ __launch_bounds__(256) void k_fwd(
    const int* __restrict__ ridx, const float* __restrict__ pw,
    const float* __restrict__ xt, const float* __restrict__ data,
    const float* __restrict__ mult, const float* __restrict__ contam,
    const float* __restrict__ norm, float* __restrict__ ratio)
{
    const int wave = threadIdx.x >> 6;
    const int lane = threadIdx.x & 63;
    const int l = blockIdx.x * 4 + wave;
    const long base = (long)l * RAYLEN;
    float ax = 0.f, ay = 0.f, az = 0.f, aw = 0.f;
#pragma unroll
    for (int k = 0; k < 4; ++k) {
        int r = lane + (k << 6);
        float wt = pw[base + r];
        float4 xv = ((const float4*)xt)[ridx[base + r]];
        ax += xv.x * wt; ay += xv.y * wt; az += xv.z * wt; aw += xv.w * wt;
    }
#pragma unroll
    for (int off = 32; off >= 1; off >>= 1) {
        ax += __shfl_xor(ax, off); ay += __shfl_xor(ay, off);
        az += __shfl_xor(az, off); aw += __shfl_xor(aw, off);
    }
    if (lane == 0) {
        float fwd[4] = {ax, ay, az, aw};
        float rr[4];
#pragma unroll
        for (int b = 0; b < 4; ++b) {
            long o = (long)b * (NSUB * NLOR) + l;
            float m = mult[o];
            float e = m * (norm[b] * fwd[b]) + contam[o];
            rr[b] = m * (1.0f - data[o] / e);
        }
        ((float4*)ratio)[l] = make_float4(rr[0], rr[1], rr[2], rr[3]);
    }
}

__global__ __launch_bounds__(1024) void k_back(
    const int* __restrict__ ridx, const float* __restrict__ pw,
    const float* __restrict__ ratio, float* __restrict__ part, int PC)
{
    __shared__ float acc[VOXT];
    const int c = blockIdx.x;
    const int g = blockIdx.y;
    const int b = g & 3;
    const int lo = (g >> 2) * VOXT;
    for (int q = threadIdx.x; q < VOXT; q += 1024) acc[q] = 0.0f;
    __syncthreads();
    const int pbeg = c * PC;
    const int pend = min(pbeg + PC, NPTS);
#pragma unroll 2
    for (int p = pbeg + (int)threadIdx.x * 4; p < pend; p += 1024 * 4) {
        int4   id = *(const int4*)(ridx + p);
        float4 w  = *(const float4*)(pw + p);
        float  r  = ratio[(p >> 8) * 4 + b];
        unsigned r0 = (unsigned)(id.x - lo), r1 = (unsigned)(id.y - lo);
        unsigned r2 = (unsigned)(id.z - lo), r3 = (unsigned)(id.w - lo);
        if (r0 < VOXT) atomicAdd(&acc[r0], w.x * r);
        if (r1 < VOXT) atomicAdd(&acc[r1], w.y * r);
        if (r2 < VOXT) atomicAdd(&acc[r2], w.z * r);
        if (r3 < VOXT) atomicAdd(&acc[r3], w.w * r);
    }
    __syncthreads();
    float4* dst = (float4*)(part + ((size_t)c * 4 + b) * NVOX + lo);
    const float4* srcl = (const float4*)acc;
    for (int q = threadIdx.x; q < VOXT / 4; q += 1024) dst[q] = srcl[q];
}
// ------------------------------------------------------------------------------------

// conv1: 1->16ch 3x3 SAME + bias + relu. Input from xt (NVOX,4), output h (B,NVOX,16).
__global__ __launch_bounds__(256) void k_conv1(
    const float* __restrict__ xt,
    const float* __restrict__ w1,  // (16,1,3,3)
    const float* __restrict__ b1,  // (16)
    float* __restrict__ h)         // (B, NVOX, 16)
{
    int t = blockIdx.x * blockDim.x + threadIdx.x;  // over B*NVOX
    int b = t >> 16;
    int v = t & 65535;
    int i = v >> 8, j = v & 255;
    float in[3][3];
#pragma unroll
    for (int di = 0; di < 3; ++di)
#pragma unroll
        for (int dj = 0; dj < 3; ++dj) {
            int ii = i + di - 1, jj = j + dj - 1;
            in[di][dj] = (ii >= 0 && ii < N0 && jj >= 0 && jj < N1)
                             ? xt[(size_t)((ii << 8) | jj) * 4 + b]
                             : 0.0f;
        }
    float* hp = h + (size_t)t * CH;
#pragma unroll
    for (int c = 0; c < CH; ++c) {
        float acc = b1[c];
#pragma unroll
        for (int di = 0; di < 3; ++di)
#pragma unroll
            for (int dj = 0; dj < 3; ++dj)
                acc += in[di][dj] * w1[c * 9 + di * 3 + dj];
        hp[c] = fmaxf(acc, 0.0f);
    }
}

// conv2 (16->1 3x3 SAME) fused with the MLEM combine; sums the C chunk partials.
__global__ __launch_bounds__(256) void k_combine(
    const float* __restrict__ h,      // (B,NVOX,16)
    const float* __restrict__ w2,     // (1,16,3,3)
    const float* __restrict__ b2,     // (1)
    const float* __restrict__ part,   // (C,4,NVOX)
    const float* __restrict__ xt_in,  // (NVOX,4)
    const float* __restrict__ osem,   // (B,NVOX)
    const float* __restrict__ adj,    // adjoint_ones + s*NVOX ; index b*NSUB*NVOX+v
    const float* __restrict__ nwp,    // scalar
    int C,
    float* __restrict__ xt_out,       // (NVOX,4)
    float* __restrict__ out_planar)   // (B,NVOX) or nullptr
{
    int t = blockIdx.x * blockDim.x + threadIdx.x;  // over B*NVOX
    int b = t >> 16;
    int v = t & 65535;
    int i = v >> 8, j = v & 255;

    float o = b2[0];
#pragma unroll
    for (int di = 0; di < 3; ++di) {
        int ii = i + di - 1;
        if (ii < 0 || ii >= N0) continue;
#pragma unroll
        for (int dj = 0; dj < 3; ++dj) {
            int jj = j + dj - 1;
            if (jj < 0 || jj >= N1) continue;
            const float* hp = h + ((size_t)b * NVOX + ((ii << 8) | jj)) * CH;
#pragma unroll
            for (int c = 0; c < CH; ++c)
                o += hp[c] * w2[c * 9 + di * 3 + dj];
        }
    }
    float bk = 0.0f;
    for (int c = 0; c < C; ++c)
        bk += part[((size_t)c * 4 + b) * NVOX + v];

    float xv = xt_in[(size_t)v * 4 + b];
    float x_data = bk * xv / adj[(size_t)b * NSUB * NVOX + v];
    float xnew = osem[t] - x_data + nwp[0] * o;
    xnew = fmaxf(xnew, 0.0f);
    xt_out[(size_t)v * 4 + b] = xnew;
    if (out_planar) out_planar[t] = xnew;
}

extern "C" void kernel_launch(void* const* d_in, const int* in_sizes, int n_in,
                              void* d_out, int out_size, void* d_ws, size_t ws_size,
                              hipStream_t stream) {
    const float* osem   = (const float*)d_in[0];
    const float* data   = (const float*)d_in[1];
    const float* mult   = (const float*)d_in[2];
    const float* contam = (const float*)d_in[3];
    const float* adj    = (const float*)d_in[4];
    const float* norm   = (const float*)d_in[5];
    const int*   ray_idx = (const int*)d_in[6];
    const float* pw     = (const float*)d_in[7];
    const float* w1     = (const float*)d_in[8];
    const float* b1     = (const float*)d_in[9];
    const float* w2     = (const float*)d_in[10];
    const float* b2     = (const float*)d_in[11];
    const float* nw     = (const float*)d_in[12];
    float* out = (float*)d_out;

    const size_t MB = 1024 * 1024;
    float* ws  = (float*)d_ws;
    float* xtA = ws;
    float* xtB = ws + (size_t)NVOX * 4;
    const int subsets[4] = {0, 2, 4, 6};

    // packed path: xtA(1M) xtB(1M) part C=32 (32M) h(16M) packed(33.5M) = ~86MB
    bool use_packed = (ws_size >= 90 * MB);

    k_transpose<<<NVOX / 256, 256, 0, stream>>>(osem, xtA);

    if (use_packed) {
        const int C = 32;
        float* part = ws + (size_t)NVOX * 8;
        float* h    = part + (size_t)C * NVOX * 4;
        float* ratio = h;  // dead before k_conv1 writes h
        unsigned* packed = (unsigned*)(h + (size_t)BB * NVOX * CH);

        float* xin = xtA;
        float* xout = xtB;
        for (int it = 0; it < 4; ++it) {
            int s = subsets[it];
            k_pack<<<NPTS / 4 / 256, 256, 0, stream>>>(
                ray_idx + (size_t)s * NPTS, pw + (size_t)s * NPTS, packed);
            k_fwd_p<<<NLOR / 4, 256, 0, stream>>>(
                packed, xin,
                data + (size_t)s * NLOR, mult + (size_t)s * NLOR,
                contam + (size_t)s * NLOR, norm, ratio);
            k_back_p<<<dim3(C, 8), 1024, 0, stream>>>(packed, ratio, part, NPTS / C);
            k_conv1<<<(BB * NVOX) / 256, 256, 0, stream>>>(xin, w1, b1, h);
            k_combine<<<(BB * NVOX) / 256, 256, 0, stream>>>(
                h, w2, b2, part, xin, osem,
                adj + (size_t)s * NVOX, nw, C,
                xout, (it == 3) ? out : nullptr);
            float* tmp = xin; xin = xout; xout = tmp;
        }
    } else {
        int C = (ws_size >= (18 + 32) * MB + NVOX) ? 32
              : (ws_size >= (18 + 16) * MB + NVOX) ? 16 : 8;
        const int PC = NPTS / C;
        float* part = ws + (size_t)NVOX * 8;
        float* h    = part + (size_t)C * NVOX * 4;
        float* ratio = h;

        float* xin = xtA;
        float* xout = xtB;
        for (int it = 0; it < 4; ++it) {
            int s = subsets[it];
            const int*   rs = ray_idx + (size_t)s * NPTS;
            const float* ps = pw + (size_t)s * NPTS;
            k_fwd<<<NLOR / 4, 256, 0, stream>>>(
                rs, ps, xin,
                data + (size_t)s * NLOR, mult + (size_t)s * NLOR,
                contam + (size_t)s * NLOR, norm, ratio);
            k_back<<<dim3(C, 8), 1024, 0, stream>>>(rs, ps, ratio, part, PC);
            k_conv1<<<(BB * NVOX) / 256, 256, 0, stream>>>(xin, w1, b1, h);
            k_combine<<<(BB * NVOX) / 256, 256, 0, stream>>>(
                h, w2, b2, part, xin, osem,
                adj + (size_t)s * NVOX, nw, C,
                xout, (it == 3) ? out : nullptr);
            float* tmp = xin; xin = xout; xout = tmp;
        }
    }
}

// Round 7
// 760.216 us; speedup vs baseline: 1.3982x; 1.3982x over previous
//
#include <hip/hip_runtime.h>
#include <hip/hip_fp16.h>

#define BB 4
#define N0 256
#define N1 256
#define NVOX 65536
#define NSUB 8
#define NLOR 32768
#define RAYLEN 256
#define CH 16
#define NPTS (NLOR * RAYLEN)
#define VOXQ 16384   // voxels per LDS quarter-plane tile (u32 f16x2 -> 64KB)
#define VOXT 32768   // fallback path tile

// Transpose osem (B, NVOX) planar -> xt (NVOX, 4) so ray gathers are one float4.
__global__ __launch_bounds__(256) void k_transpose(const float* __restrict__ osem,
                                                   float* __restrict__ xt) {
    int v = blockIdx.x * blockDim.x + threadIdx.x;
    if (v >= NVOX) return;
    float4 o;
    o.x = osem[0 * NVOX + v];
    o.y = osem[1 * NVOX + v];
    o.z = osem[2 * NVOX + v];
    o.w = osem[3 * NVOX + v];
    ((float4*)xt)[v] = o;
}

// Pack one subset's ray data: u32 = u16 voxel idx | f16 weight.
__global__ __launch_bounds__(256) void k_pack(const int* __restrict__ ridx,
                                              const float* __restrict__ pw,
                                              unsigned* __restrict__ packed) {
    int t = blockIdx.x * blockDim.x + threadIdx.x;  // over NPTS/4
    int4   id = ((const int4*)ridx)[t];
    float4 w  = ((const float4*)pw)[t];
    uint4 o;
    o.x = (unsigned)id.x | ((unsigned)__half_as_ushort(__float2half_rn(w.x)) << 16);
    o.y = (unsigned)id.y | ((unsigned)__half_as_ushort(__float2half_rn(w.y)) << 16);
    o.z = (unsigned)id.z | ((unsigned)__half_as_ushort(__float2half_rn(w.z)) << 16);
    o.w = (unsigned)id.w | ((unsigned)__half_as_ushort(__float2half_rn(w.w)) << 16);
    ((uint4*)packed)[t] = o;
}

__device__ __forceinline__ float upk_w(unsigned p) {
    return __half2float(__ushort_as_half((unsigned short)(p >> 16)));
}

__device__ __forceinline__ unsigned pk2(float a, float b) {
    __half2 h = __floats2half2_rn(a, b);
    return *reinterpret_cast<unsigned*>(&h);
}

// Forward projection + ratio per LOR (packed input). One wave per LOR.
__global__ __launch_bounds__(256) void k_fwd_p(
    const unsigned* __restrict__ packed,
    const float* __restrict__ xt,         // (NVOX,4)
    const float* __restrict__ data,       // + index b*NSUB*NLOR + l
    const float* __restrict__ mult,
    const float* __restrict__ contam,
    const float* __restrict__ norm,       // (B)
    float* __restrict__ ratio)            // (NLOR,4)
{
    const int wave = threadIdx.x >> 6;
    const int lane = threadIdx.x & 63;
    const int l = blockIdx.x * 4 + wave;

    uint4 P = ((const uint4*)(packed + (size_t)l * RAYLEN))[lane];
    float ax = 0.f, ay = 0.f, az = 0.f, aw = 0.f;
    unsigned pp[4] = {P.x, P.y, P.z, P.w};
#pragma unroll
    for (int k = 0; k < 4; ++k) {
        float wt = upk_w(pp[k]);
        float4 xv = ((const float4*)xt)[pp[k] & 0xffffu];
        ax += xv.x * wt;
        ay += xv.y * wt;
        az += xv.z * wt;
        aw += xv.w * wt;
    }
#pragma unroll
    for (int off = 32; off >= 1; off >>= 1) {
        ax += __shfl_xor(ax, off);
        ay += __shfl_xor(ay, off);
        az += __shfl_xor(az, off);
        aw += __shfl_xor(aw, off);
    }
    if (lane == 0) {
        float fwd[4] = {ax, ay, az, aw};
        float rr[4];
#pragma unroll
        for (int b = 0; b < 4; ++b) {
            long o = (long)b * (NSUB * NLOR) + l;
            float m = mult[o];
            float e = m * (norm[b] * fwd[b]) + contam[o];
            rr[b] = m * (1.0f - data[o] / e);
        }
        ((float4*)ratio)[l] = make_float4(rr[0], rr[1], rr[2], rr[3]);
    }
}

// Backprojection with PACKED f16x2 LDS atomics (ds_pk_add_f16 via inline asm):
// block (chunk c, group g) owns batch-pair p=g&1 and voxel quarter g>>1.
// One pk-atomic covers BOTH batches -> lane-RMW count halves vs f32 path.
// 64KB LDS -> 2 blocks/CU (32 waves) for extra latency hiding.
__global__ __launch_bounds__(1024) void k_back_pk(
    const unsigned* __restrict__ packed,  // subset's packed stream
    const float* __restrict__ ratio,      // (NLOR,4) = (NLOR,2) float2 pairs
    unsigned* __restrict__ part,          // (C, 2, NVOX) f16x2 partials
    int PC)                               // points per chunk
{
    __shared__ unsigned acc[VOXQ];
    const int c = blockIdx.x;
    const int g = blockIdx.y;             // 0..7
    const int p = g & 1;                  // batch pair (batches 2p, 2p+1)
    const unsigned lo = (unsigned)(g >> 1) * VOXQ;

    for (int q = threadIdx.x; q < VOXQ; q += 1024) acc[q] = 0u;
    __syncthreads();

    // low 32 bits of a flat shared-memory pointer = LDS byte offset (HK idiom)
    const unsigned abase = (unsigned)(uintptr_t)(&acc[0]);

    const int n4 = PC >> 2;                         // uint4 elems in this chunk
    const uint4* src = (const uint4*)packed + (size_t)c * n4;
    const float2* rat2 = (const float2*)ratio;
    const int e0 = c * n4;

#define PKADD(u, R)                                                              \
    {                                                                            \
        unsigned q_ = ((u) & 0xffffu) - lo;                                      \
        if (q_ < VOXQ) {                                                         \
            float w_ = upk_w(u);                                                 \
            unsigned d_ = pk2(w_ * (R).x, w_ * (R).y);                           \
            unsigned a_ = abase + (q_ << 2);                                     \
            asm volatile("ds_pk_add_f16 %0, %1" :: "v"(a_), "v"(d_) : "memory"); \
        }                                                                        \
    }
#define PROC(P, R) PKADD(P.x, R) PKADD(P.y, R) PKADD(P.z, R) PKADD(P.w, R)

    for (int base4 = 0; base4 < n4; base4 += 4096) {
        const int ea = base4 + (int)threadIdx.x;
        uint4 A = src[ea];
        uint4 B = src[ea + 1024];
        uint4 C2 = src[ea + 2048];
        uint4 D = src[ea + 3072];
        float2 ra = rat2[(((e0 + ea) >> 6) << 1) + p];
        float2 rb = rat2[(((e0 + ea + 1024) >> 6) << 1) + p];
        float2 rc = rat2[(((e0 + ea + 2048) >> 6) << 1) + p];
        float2 rd = rat2[(((e0 + ea + 3072) >> 6) << 1) + p];
        PROC(A, ra) PROC(B, rb) PROC(C2, rc) PROC(D, rd)
    }
#undef PROC
#undef PKADD

    // drain our asm ds ops (compiler doesn't track them) before the barrier
    asm volatile("s_waitcnt lgkmcnt(0)" ::: "memory");
    __syncthreads();

    unsigned* dst = part + ((size_t)c * 2 + p) * NVOX + lo;
    for (int q = threadIdx.x; q < VOXQ; q += 1024) dst[q] = acc[q];
}

// ---------------- raw fallback (R3 path, used if workspace is small) ----------------
__global__ __launch_bounds__(256) void k_fwd(
    const int* __restrict__ ridx, const float* __restrict__ pw,
    const float* __restrict__ xt, const float* __restrict__ data,
    const float* __restrict__ mult, const float* __restrict__ contam,
    const float* __restrict__ norm, float* __restrict__ ratio)
{
    const int wave = threadIdx.x >> 6;
    const int lane = threadIdx.x & 63;
    const int l = blockIdx.x * 4 + wave;
    const long base = (long)l * RAYLEN;
    float ax = 0.f, ay = 0.f, az = 0.f, aw = 0.f;
#pragma unroll
    for (int k = 0; k < 4; ++k) {
        int r = lane + (k << 6);
        float wt = pw[base + r];
        float4 xv = ((const float4*)xt)[ridx[base + r]];
        ax += xv.x * wt; ay += xv.y * wt; az += xv.z * wt; aw += xv.w * wt;
    }
#pragma unroll
    for (int off = 32; off >= 1; off >>= 1) {
        ax += __shfl_xor(ax, off); ay += __shfl_xor(ay, off);
        az += __shfl_xor(az, off); aw += __shfl_xor(aw, off);
    }
    if (lane == 0) {
        float fwd[4] = {ax, ay, az, aw};
        float rr[4];
#pragma unroll
        for (int b = 0; b < 4; ++b) {
            long o = (long)b * (NSUB * NLOR) + l;
            float m = mult[o];
            float e = m * (norm[b] * fwd[b]) + contam[o];
            rr[b] = m * (1.0f - data[o] / e);
        }
        ((float4*)ratio)[l] = make_float4(rr[0], rr[1], rr[2], rr[3]);
    }
}

__global__ __launch_bounds__(1024) void k_back(
    const int* __restrict__ ridx, const float* __restrict__ pw,
    const float* __restrict__ ratio, float* __restrict__ part, int PC)
{
    __shared__ float acc[VOXT];
    const int c = blockIdx.x;
    const int g = blockIdx.y;
    const int b = g & 3;
    const int lo = (g >> 2) * VOXT;
    for (int q = threadIdx.x; q < VOXT; q += 1024) acc[q] = 0.0f;
    __syncthreads();
    const int pbeg = c * PC;
    const int pend = min(pbeg + PC, NPTS);
#pragma unroll 2
    for (int pt = pbeg + (int)threadIdx.x * 4; pt < pend; pt += 1024 * 4) {
        int4   id = *(const int4*)(ridx + pt);
        float4 w  = *(const float4*)(pw + pt);
        float  r  = ratio[(pt >> 8) * 4 + b];
        unsigned r0 = (unsigned)(id.x - lo), r1 = (unsigned)(id.y - lo);
        unsigned r2 = (unsigned)(id.z - lo), r3 = (unsigned)(id.w - lo);
        if (r0 < VOXT) atomicAdd(&acc[r0], w.x * r);
        if (r1 < VOXT) atomicAdd(&acc[r1], w.y * r);
        if (r2 < VOXT) atomicAdd(&acc[r2], w.z * r);
        if (r3 < VOXT) atomicAdd(&acc[r3], w.w * r);
    }
    __syncthreads();
    float4* dst = (float4*)(part + ((size_t)c * 4 + b) * NVOX + lo);
    const float4* srcl = (const float4*)acc;
    for (int q = threadIdx.x; q < VOXT / 4; q += 1024) dst[q] = srcl[q];
}
// ------------------------------------------------------------------------------------

// conv1: 1->16ch 3x3 SAME + bias + relu. Input from xt (NVOX,4), output h (B,NVOX,16).
__global__ __launch_bounds__(256) void k_conv1(
    const float* __restrict__ xt,
    const float* __restrict__ w1,  // (16,1,3,3)
    const float* __restrict__ b1,  // (16)
    float* __restrict__ h)         // (B, NVOX, 16)
{
    int t = blockIdx.x * blockDim.x + threadIdx.x;  // over B*NVOX
    int b = t >> 16;
    int v = t & 65535;
    int i = v >> 8, j = v & 255;
    float in[3][3];
#pragma unroll
    for (int di = 0; di < 3; ++di)
#pragma unroll
        for (int dj = 0; dj < 3; ++dj) {
            int ii = i + di - 1, jj = j + dj - 1;
            in[di][dj] = (ii >= 0 && ii < N0 && jj >= 0 && jj < N1)
                             ? xt[(size_t)((ii << 8) | jj) * 4 + b]
                             : 0.0f;
        }
    float* hp = h + (size_t)t * CH;
#pragma unroll
    for (int c = 0; c < CH; ++c) {
        float acc = b1[c];
#pragma unroll
        for (int di = 0; di < 3; ++di)
#pragma unroll
            for (int dj = 0; dj < 3; ++dj)
                acc += in[di][dj] * w1[c * 9 + di * 3 + dj];
        hp[c] = fmaxf(acc, 0.0f);
    }
}

// conv2 (16->1 3x3 SAME) fused with the MLEM combine; sums f16x2 chunk partials.
__global__ __launch_bounds__(256) void k_combine_pk(
    const float* __restrict__ h,      // (B,NVOX,16)
    const float* __restrict__ w2,     // (1,16,3,3)
    const float* __restrict__ b2,     // (1)
    const unsigned* __restrict__ part,// (C,2,NVOX) f16x2
    const float* __restrict__ xt_in,  // (NVOX,4)
    const float* __restrict__ osem,   // (B,NVOX)
    const float* __restrict__ adj,    // adjoint_ones + s*NVOX ; index b*NSUB*NVOX+v
    const float* __restrict__ nwp,    // scalar
    int C,
    float* __restrict__ xt_out,       // (NVOX,4)
    float* __restrict__ out_planar)   // (B,NVOX) or nullptr
{
    int t = blockIdx.x * blockDim.x + threadIdx.x;  // over B*NVOX
    int b = t >> 16;
    int v = t & 65535;
    int i = v >> 8, j = v & 255;

    float o = b2[0];
#pragma unroll
    for (int di = 0; di < 3; ++di) {
        int ii = i + di - 1;
        if (ii < 0 || ii >= N0) continue;
#pragma unroll
        for (int dj = 0; dj < 3; ++dj) {
            int jj = j + dj - 1;
            if (jj < 0 || jj >= N1) continue;
            const float* hp = h + ((size_t)b * NVOX + ((ii << 8) | jj)) * CH;
#pragma unroll
            for (int c = 0; c < CH; ++c)
                o += hp[c] * w2[c * 9 + di * 3 + dj];
        }
    }
    // sum the per-chunk f16x2 partials (batch b = pair b>>1, half b&1)
    const int pr = b >> 1, hi = b & 1;
    float bk = 0.0f;
    for (int c = 0; c < C; ++c) {
        unsigned u = part[((size_t)c * 2 + pr) * NVOX + v];
        unsigned short us = hi ? (unsigned short)(u >> 16) : (unsigned short)(u & 0xffffu);
        bk += __half2float(__ushort_as_half(us));
    }

    float xv = xt_in[(size_t)v * 4 + b];
    float x_data = bk * xv / adj[(size_t)b * NSUB * NVOX + v];
    float xnew = osem[t] - x_data + nwp[0] * o;
    xnew = fmaxf(xnew, 0.0f);
    xt_out[(size_t)v * 4 + b] = xnew;
    if (out_planar) out_planar[t] = xnew;
}

// f32-partial combine for the fallback path.
__global__ __launch_bounds__(256) void k_combine(
    const float* __restrict__ h, const float* __restrict__ w2,
    const float* __restrict__ b2, const float* __restrict__ part,
    const float* __restrict__ xt_in, const float* __restrict__ osem,
    const float* __restrict__ adj, const float* __restrict__ nwp, int C,
    float* __restrict__ xt_out, float* __restrict__ out_planar)
{
    int t = blockIdx.x * blockDim.x + threadIdx.x;
    int b = t >> 16;
    int v = t & 65535;
    int i = v >> 8, j = v & 255;
    float o = b2[0];
#pragma unroll
    for (int di = 0; di < 3; ++di) {
        int ii = i + di - 1;
        if (ii < 0 || ii >= N0) continue;
#pragma unroll
        for (int dj = 0; dj < 3; ++dj) {
            int jj = j + dj - 1;
            if (jj < 0 || jj >= N1) continue;
            const float* hp = h + ((size_t)b * NVOX + ((ii << 8) | jj)) * CH;
#pragma unroll
            for (int c = 0; c < CH; ++c)
                o += hp[c] * w2[c * 9 + di * 3 + dj];
        }
    }
    float bk = 0.0f;
    for (int c = 0; c < C; ++c)
        bk += part[((size_t)c * 4 + b) * NVOX + v];
    float xv = xt_in[(size_t)v * 4 + b];
    float x_data = bk * xv / adj[(size_t)b * NSUB * NVOX + v];
    float xnew = osem[t] - x_data + nwp[0] * o;
    xnew = fmaxf(xnew, 0.0f);
    xt_out[(size_t)v * 4 + b] = xnew;
    if (out_planar) out_planar[t] = xnew;
}

extern "C" void kernel_launch(void* const* d_in, const int* in_sizes, int n_in,
                              void* d_out, int out_size, void* d_ws, size_t ws_size,
                              hipStream_t stream) {
    const float* osem   = (const float*)d_in[0];
    const float* data   = (const float*)d_in[1];
    const float* mult   = (const float*)d_in[2];
    const float* contam = (const float*)d_in[3];
    const float* adj    = (const float*)d_in[4];
    const float* norm   = (const float*)d_in[5];
    const int*   ray_idx = (const int*)d_in[6];
    const float* pw     = (const float*)d_in[7];
    const float* w1     = (const float*)d_in[8];
    const float* b1     = (const float*)d_in[9];
    const float* w2     = (const float*)d_in[10];
    const float* b2     = (const float*)d_in[11];
    const float* nw     = (const float*)d_in[12];
    float* out = (float*)d_out;

    const size_t MB = 1024 * 1024;
    float* ws  = (float*)d_ws;
    float* xtA = ws;
    float* xtB = ws + (size_t)NVOX * 4;
    const int subsets[4] = {0, 2, 4, 6};

    // pk path: xtA(1M) xtB(1M) part f16x2 C=64 (33.5M) h(16M) packed(33.5M) = ~85MB
    bool use_pk = (ws_size >= 90 * MB);

    k_transpose<<<NVOX / 256, 256, 0, stream>>>(osem, xtA);

    if (use_pk) {
        const int C = 64;
        const int PC = NPTS / C;  // 131072
        unsigned* part = (unsigned*)(ws + (size_t)NVOX * 8);
        float* h    = (float*)(part + (size_t)C * 2 * NVOX);
        float* ratio = h;  // dead before k_conv1 writes h
        unsigned* packed = (unsigned*)(h + (size_t)BB * NVOX * CH);

        float* xin = xtA;
        float* xout = xtB;
        for (int it = 0; it < 4; ++it) {
            int s = subsets[it];
            k_pack<<<NPTS / 4 / 256, 256, 0, stream>>>(
                ray_idx + (size_t)s * NPTS, pw + (size_t)s * NPTS, packed);
            k_fwd_p<<<NLOR / 4, 256, 0, stream>>>(
                packed, xin,
                data + (size_t)s * NLOR, mult + (size_t)s * NLOR,
                contam + (size_t)s * NLOR, norm, ratio);
            k_back_pk<<<dim3(C, 8), 1024, 0, stream>>>(packed, ratio, part, PC);
            k_conv1<<<(BB * NVOX) / 256, 256, 0, stream>>>(xin, w1, b1, h);
            k_combine_pk<<<(BB * NVOX) / 256, 256, 0, stream>>>(
                h, w2, b2, part, xin, osem,
                adj + (size_t)s * NVOX, nw, C,
                xout, (it == 3) ? out : nullptr);
            float* tmp = xin; xin = xout; xout = tmp;
        }
    } else {
        int C = (ws_size >= (18 + 32) * MB + NVOX) ? 32
              : (ws_size >= (18 + 16) * MB + NVOX) ? 16 : 8;
        const int PC = NPTS / C;
        float* part = ws + (size_t)NVOX * 8;
        float* h    = part + (size_t)C * NVOX * 4;
        float* ratio = h;

        float* xin = xtA;
        float* xout = xtB;
        for (int it = 0; it < 4; ++it) {
            int s = subsets[it];
            const int*   rs = ray_idx + (size_t)s * NPTS;
            const float* ps = pw + (size_t)s * NPTS;
            k_fwd<<<NLOR / 4, 256, 0, stream>>>(
                rs, ps, xin,
                data + (size_t)s * NLOR, mult + (size_t)s * NLOR,
                contam + (size_t)s * NLOR, norm, ratio);
            k_back<<<dim3(C, 8), 1024, 0, stream>>>(rs, ps, ratio, part, PC);
            k_conv1<<<(BB * NVOX) / 256, 256, 0, stream>>>(xin, w1, b1, h);
            k_combine<<<(BB * NVOX) / 256, 256, 0, stream>>>(
                h, w2, b2, part, xin, osem,
                adj + (size_t)s * NVOX, nw, C,
                xout, (it == 3) ? out : nullptr);
            float* tmp = xin; xin = xout; xout = tmp;
        }
    }
}